// Round 3
// baseline (29.502 us; speedup 1.0000x reference)
//
#include <hip/hip_runtime.h>
#include <math.h>

// SGO_Loss_Prod: B=16, N=256 atoms, K=16 ops, r=0.4.
// Min-image collapse (r<0.5 -> at most one periodic shift passes the mask):
// validated bit-exact R1/R2. Rotational half-shell weight-2 (R2).
// R3: single fused dispatch. Last-arriving block (atomicDec wrap trick)
// performs the final norm-reduction. No second kernel node, no memset.

#define NATOMS 256
#define KOPS   16
#define NB     16
#define TASKS_PER_B (KOPS + 1)   // identity + 16 ops
#define JSPLIT 4                 // t-range 1..128 split 4 ways
#define TCHUNK 32
#define NBLK   (NB * TASKS_PER_B * JSPLIT)   // 1088
#define CTR_OFF 13312            // byte offset of counter in ws (sums = 13056 B)

// Replicates jnp.mod(x, 1.0) (validated bit-exact in R1).
__device__ __forceinline__ float wrap01(float x) {
    float m = fmodf(x, 1.0f);
    if (m < 0.0f) m += 1.0f;
    return m;
}

__device__ __forceinline__ void agent_store(float* p, float v) {
    __hip_atomic_store(p, v, __ATOMIC_RELAXED, __HIP_MEMORY_SCOPE_AGENT);
}
__device__ __forceinline__ float agent_load(const float* p) {
    return __hip_atomic_load(p, __ATOMIC_RELAXED, __HIP_MEMORY_SCOPE_AGENT);
}

__global__ __launch_bounds__(256) void sgo_fused_kernel(
    const float* __restrict__ fracs,
    const float* __restrict__ oprss,
    float* __restrict__ sums,         // ws: [NBLK][3] floats
    unsigned int* __restrict__ ctr,   // ws + CTR_OFF
    float* __restrict__ out)
{
    const int blk  = blockIdx.x;      // 0..1087
    const int task = blk >> 2;        // 0..271
    const int q    = blk & 3;         // t-chunk
    const int b    = task / TASKS_PER_B;
    const int t    = task - b * TASKS_PER_B;   // 0 = identity, 1..16 = op t-1

    const int i = threadIdx.x;        // src atom
    const float* f = fracs + (size_t)b * NATOMS * 3;

    __shared__ float4 sf[NATOMS];
    __shared__ int sh_last;

    float fx = f[i*3+0], fy = f[i*3+1], fz = f[i*3+2];
    if (t > 0) {
        const float* op = oprss + (size_t)(b * KOPS + (t - 1)) * 9;
        // f1[i] = f[i] @ opr.T ; component c = dot(opr row c, f[i]); then mod 1
        float gx = wrap01(fx*op[0] + fy*op[1] + fz*op[2]);
        float gy = wrap01(fx*op[3] + fy*op[4] + fz*op[5]);
        float gz = wrap01(fx*op[6] + fy*op[7] + fz*op[8]);
        fx = gx; fy = gy; fz = gz;
    }
    sf[i] = make_float4(fx, fy, fz, 0.0f);
    __syncthreads();

    // weight-2 accumulation over t = tbase .. tbase+31 (half-shell)
    float a0 = 0.f, a1 = 0.f, a2 = 0.f;
    const int tbase = q * TCHUNK + 1;
    #pragma unroll 8
    for (int u = 0; u < TCHUNK; ++u) {
        const int j = (i + tbase + u) & (NATOMS - 1);
        const float4 fj = sf[j];                 // ds_read_b128, broadcast-friendly
        float dx = fj.x - fx, dy = fj.y - fy, dz = fj.z - fz;
        // (dst + shift) - src ordering matches reference rounding (bit-exact)
        float vx = (fj.x - rintf(dx)) - fx;
        float vy = (fj.y - rintf(dy)) - fy;
        float vz = (fj.z - rintf(dz)) - fz;
        float px = vx*vx, py = vy*vy, pz = vz*vz;
        float d2 = px + py + pz;
        float m = (d2 <= 0.4f*0.4f) ? 1.0f : 0.0f;
        a0 = fmaf(px, m, a0);
        a1 = fmaf(py, m, a1);
        a2 = fmaf(pz, m, a2);
    }
    a0 *= 2.0f; a1 *= 2.0f; a2 *= 2.0f;

    // t = 128 was counted at weight 2 by chunk q==3; net weight must be 1.
    if (q == 3) {
        const int j = (i + 128) & (NATOMS - 1);
        const float4 fj = sf[j];
        float dx = fj.x - fx, dy = fj.y - fy, dz = fj.z - fz;
        float vx = (fj.x - rintf(dx)) - fx;
        float vy = (fj.y - rintf(dy)) - fy;
        float vz = (fj.z - rintf(dz)) - fz;
        float px = vx*vx, py = vy*vy, pz = vz*vz;
        float d2 = px + py + pz;
        float m = (d2 <= 0.4f*0.4f) ? 1.0f : 0.0f;
        a0 = fmaf(px, -m, a0);
        a1 = fmaf(py, -m, a1);
        a2 = fmaf(pz, -m, a2);
    }

    // wave64 butterfly reduce
    for (int off = 32; off >= 1; off >>= 1) {
        a0 += __shfl_xor(a0, off);
        a1 += __shfl_xor(a1, off);
        a2 += __shfl_xor(a2, off);
    }
    __shared__ float part[4][3];
    const int wave = i >> 6;
    if ((i & 63) == 0) { part[wave][0] = a0; part[wave][1] = a1; part[wave][2] = a2; }
    __syncthreads();

    if (i == 0) {
        float* dst = sums + (size_t)blk * 3;
        // agent-scope stores: bypass non-coherent per-XCD L2 (G16)
        agent_store(&dst[0], part[0][0] + part[1][0] + part[2][0] + part[3][0]);
        agent_store(&dst[1], part[0][1] + part[1][1] + part[2][1] + part[3][1]);
        agent_store(&dst[2], part[0][2] + part[1][2] + part[2][2] + part[3][2]);
        __threadfence();   // release: rows visible before the arrival tick
        // atomicDec wrap: old==0 || old>1087 -> 1087, else old-1.
        // Self-heals from start in {0} U (1087, inf): zeroed fresh alloc,
        // 0xAAAAAAAA poison, and steady-state end value 0 all give the
        // detector (old==1) exactly on the 1088th arrival.
        unsigned int old = atomicDec(ctr, NBLK - 1);   // val = 1087
        sh_last = (old == 1u) ? 1 : 0;
    }
    __syncthreads();

    if (sh_last) {
        // ---- finish phase: this (last) block reduces all 1088 rows ----
        __threadfence();   // acquire side
        const int tt = i;                 // 0..255 -> (b,k)
        const int fb = tt >> 4, fk = tt & 15;
        const float* s0p = sums + (size_t)((fb * TASKS_PER_B + 0)      * JSPLIT) * 3;
        const float* skp = sums + (size_t)((fb * TASKS_PER_B + 1 + fk) * JSPLIT) * 3;
        float s0x = 0.f, s0y = 0.f, s0z = 0.f;
        float skx = 0.f, sky = 0.f, skz = 0.f;
        #pragma unroll
        for (int qq = 0; qq < JSPLIT; ++qq) {
            s0x += agent_load(&s0p[qq*3+0]);
            s0y += agent_load(&s0p[qq*3+1]);
            s0z += agent_load(&s0p[qq*3+2]);
            skx += agent_load(&skp[qq*3+0]);
            sky += agent_load(&skp[qq*3+1]);
            skz += agent_load(&skp[qq*3+2]);
        }
        float d0 = skx - s0x, d1 = sky - s0y, d2 = skz - s0z;
        float v = sqrtf(d0*d0 + d1*d1 + d2*d2);

        for (int off = 32; off >= 1; off >>= 1) v += __shfl_xor(v, off);
        if ((tt & 63) == 0) part[tt >> 6][0] = v;
        __syncthreads();
        if (tt == 0) {
            float total = part[0][0] + part[1][0] + part[2][0] + part[3][0];
            agent_store(out, total * (1.0f / 256.0f));
        }
    }
}

extern "C" void kernel_launch(void* const* d_in, const int* in_sizes, int n_in,
                              void* d_out, int out_size, void* d_ws, size_t ws_size,
                              hipStream_t stream) {
    const float* fracs = (const float*)d_in[0];
    const float* oprss = (const float*)d_in[2];
    float* out  = (float*)d_out;
    float* sums = (float*)d_ws;                                  // 13056 B
    unsigned int* ctr = (unsigned int*)((char*)d_ws + CTR_OFF);  // 4 B

    sgo_fused_kernel<<<NBLK, 256, 0, stream>>>(fracs, oprss, sums, ctr, out);
}

// Round 4
// 24.480 us; speedup vs baseline: 1.2051x; 1.2051x over previous
//
#include <hip/hip_runtime.h>
#include <math.h>

// SGO_Loss_Prod: B=16, N=256 atoms, K=16 ops, r=0.4.
// Min-image collapse (r<0.5 -> at most one periodic shift can pass the mask):
// validated bit-exact R1/R2. Rotational half-shell weight-2 (R2, absmax 0.0).
// R4: one block per (b,k) computes BOTH identity and op sums (identity
// redundantly, 16x) -> block-local norm -> single relaxed atomicAdd.
// No cross-block fences (R3 lesson: threadfence+counter cost ~15us).

#define NATOMS 256
#define KOPS   16
#define NB     16

// Replicates jnp.mod(x, 1.0) (validated bit-exact in R1).
__device__ __forceinline__ float wrap01(float x) {
    float m = fmodf(x, 1.0f);
    if (m < 0.0f) m += 1.0f;
    return m;
}

__global__ __launch_bounds__(1024) void sgo_kernel(
    const float* __restrict__ fracs,
    const float* __restrict__ oprss,
    float* __restrict__ out)
{
    const int blk = blockIdx.x;       // 0..255 = (b,k)
    const int b   = blk >> 4;
    const int k   = blk & 15;
    const int tid = threadIdx.x;      // 0..1023
    const int i   = tid & (NATOMS - 1);   // atom
    const int q   = tid >> 8;             // t-chunk 0..3

    const float* f = fracs + (size_t)b * NATOMS * 3;

    __shared__ float4 sfi[NATOMS];    // identity coords
    __shared__ float4 sfo[NATOMS];    // op-transformed coords

    if (q == 0) {
        float fx = f[i*3+0], fy = f[i*3+1], fz = f[i*3+2];
        sfi[i] = make_float4(fx, fy, fz, 0.0f);
    } else if (q == 1) {
        float fx = f[i*3+0], fy = f[i*3+1], fz = f[i*3+2];
        const float* op = oprss + (size_t)(b * KOPS + k) * 9;
        // same source expression as R2 (bit-exact validated)
        float gx = wrap01(fx*op[0] + fy*op[1] + fz*op[2]);
        float gy = wrap01(fx*op[3] + fy*op[4] + fz*op[5]);
        float gz = wrap01(fx*op[6] + fy*op[7] + fz*op[8]);
        sfo[i] = make_float4(gx, gy, gz, 0.0f);
    }
    __syncthreads();

    const float4 fi4 = sfi[i];
    const float4 fo4 = sfo[i];

    // half-shell, weight 2: this thread covers t = q*32+1 .. q*32+32
    float a0 = 0.f, a1 = 0.f, a2 = 0.f;   // identity
    float c0 = 0.f, c1 = 0.f, c2 = 0.f;   // op-k
    const int tbase = q * 32 + 1;
    #pragma unroll 8
    for (int u = 0; u < 32; ++u) {
        const int j = (i + tbase + u) & (NATOMS - 1);
        {   // identity set
            const float4 fj = sfi[j];
            float dx = fj.x - fi4.x, dy = fj.y - fi4.y, dz = fj.z - fi4.z;
            float vx = (fj.x - rintf(dx)) - fi4.x;
            float vy = (fj.y - rintf(dy)) - fi4.y;
            float vz = (fj.z - rintf(dz)) - fi4.z;
            float px = vx*vx, py = vy*vy, pz = vz*vz;
            float d2 = px + py + pz;
            float m = (d2 <= 0.4f*0.4f) ? 1.0f : 0.0f;
            a0 = fmaf(px, m, a0);
            a1 = fmaf(py, m, a1);
            a2 = fmaf(pz, m, a2);
        }
        {   // op set
            const float4 fj = sfo[j];
            float dx = fj.x - fo4.x, dy = fj.y - fo4.y, dz = fj.z - fo4.z;
            float vx = (fj.x - rintf(dx)) - fo4.x;
            float vy = (fj.y - rintf(dy)) - fo4.y;
            float vz = (fj.z - rintf(dz)) - fo4.z;
            float px = vx*vx, py = vy*vy, pz = vz*vz;
            float d2 = px + py + pz;
            float m = (d2 <= 0.4f*0.4f) ? 1.0f : 0.0f;
            c0 = fmaf(px, m, c0);
            c1 = fmaf(py, m, c1);
            c2 = fmaf(pz, m, c2);
        }
    }
    a0 *= 2.0f; a1 *= 2.0f; a2 *= 2.0f;
    c0 *= 2.0f; c1 *= 2.0f; c2 *= 2.0f;

    // t=128 was counted at weight 2 by q==3; both endpoints visit it, so net
    // weight must be 1 per visit (ordered-pair count = 2). Subtract one eval.
    if (q == 3) {
        const int j = (i + 128) & (NATOMS - 1);
        {
            const float4 fj = sfi[j];
            float dx = fj.x - fi4.x, dy = fj.y - fi4.y, dz = fj.z - fi4.z;
            float vx = (fj.x - rintf(dx)) - fi4.x;
            float vy = (fj.y - rintf(dy)) - fi4.y;
            float vz = (fj.z - rintf(dz)) - fi4.z;
            float px = vx*vx, py = vy*vy, pz = vz*vz;
            float d2 = px + py + pz;
            float m = (d2 <= 0.4f*0.4f) ? 1.0f : 0.0f;
            a0 = fmaf(px, -m, a0);
            a1 = fmaf(py, -m, a1);
            a2 = fmaf(pz, -m, a2);
        }
        {
            const float4 fj = sfo[j];
            float dx = fj.x - fo4.x, dy = fj.y - fo4.y, dz = fj.z - fo4.z;
            float vx = (fj.x - rintf(dx)) - fo4.x;
            float vy = (fj.y - rintf(dy)) - fo4.y;
            float vz = (fj.z - rintf(dz)) - fo4.z;
            float px = vx*vx, py = vy*vy, pz = vz*vz;
            float d2 = px + py + pz;
            float m = (d2 <= 0.4f*0.4f) ? 1.0f : 0.0f;
            c0 = fmaf(px, -m, c0);
            c1 = fmaf(py, -m, c1);
            c2 = fmaf(pz, -m, c2);
        }
    }

    // reduce (s_k - s_0) = sum over threads of (c - a)   [linearity]
    float d0 = c0 - a0, d1 = c1 - a1, d2 = c2 - a2;
    for (int off = 32; off >= 1; off >>= 1) {
        d0 += __shfl_xor(d0, off);
        d1 += __shfl_xor(d1, off);
        d2 += __shfl_xor(d2, off);
    }
    __shared__ float part[16][3];
    const int wave = tid >> 6;
    if ((tid & 63) == 0) { part[wave][0] = d0; part[wave][1] = d1; part[wave][2] = d2; }
    __syncthreads();

    if (tid == 0) {
        float sx = 0.f, sy = 0.f, sz = 0.f;
        #pragma unroll
        for (int w = 0; w < 16; ++w) {
            sx += part[w][0]; sy += part[w][1]; sz += part[w][2];
        }
        float v = sqrtf(sx*sx + sy*sy + sz*sz);
        atomicAdd(out, v * (1.0f / 256.0f));
    }
}

extern "C" void kernel_launch(void* const* d_in, const int* in_sizes, int n_in,
                              void* d_out, int out_size, void* d_ws, size_t ws_size,
                              hipStream_t stream) {
    const float* fracs = (const float*)d_in[0];
    const float* oprss = (const float*)d_in[2];
    float* out = (float*)d_out;

    hipMemsetAsync(out, 0, sizeof(float), stream);   // graph-capturable memset node
    sgo_kernel<<<NB * KOPS, 1024, 0, stream>>>(fracs, oprss, out);
}

// Round 5
// 21.156 us; speedup vs baseline: 1.3945x; 1.1571x over previous
//
#include <hip/hip_runtime.h>
#include <math.h>

// SGO_Loss_Prod: B=16, N=256 atoms, K=16 ops, r=0.4.
// Min-image collapse (r<0.5 -> at most one periodic shift can pass the mask):
// validated bit-exact R1/R2. Rotational half-shell weight-2 (R2, absmax 0.0).
// R4 body: one block per (b,k), identity recomputed per block.
// R5: single kernel node, NO memset, NO fences. Final combine via wait-free
// atomic chain: atomicAdd(acc) -> (laundered order) -> atomicDec(ctr,255);
// 256th arrival (old==1, self-healing from 0 / 0xAA poison / steady 0)
// exchanges acc to 0 (reset for next replay) and plain-stores out.
// R3 lesson: threadfence per block = ~15us; atomics alone are staggered+cheap.

#define NATOMS 256
#define KOPS   16
#define NB     16

// Replicates jnp.mod(x, 1.0) (validated bit-exact in R1).
__device__ __forceinline__ float wrap01(float x) {
    float m = fmodf(x, 1.0f);
    if (m < 0.0f) m += 1.0f;
    return m;
}

__global__ __launch_bounds__(1024) void sgo_kernel(
    const float* __restrict__ fracs,
    const float* __restrict__ oprss,
    float* __restrict__ acc,          // ws + 0   (float accumulator)
    unsigned int* __restrict__ ctr,   // ws + 128 (arrival counter)
    float* __restrict__ out)
{
    const int blk = blockIdx.x;       // 0..255 = (b,k)
    const int b   = blk >> 4;
    const int k   = blk & 15;
    const int tid = threadIdx.x;      // 0..1023
    const int i   = tid & (NATOMS - 1);   // atom
    const int q   = tid >> 8;             // t-chunk 0..3

    const float* f = fracs + (size_t)b * NATOMS * 3;

    __shared__ float4 sfi[NATOMS];    // identity coords
    __shared__ float4 sfo[NATOMS];    // op-transformed coords

    if (q == 0) {
        float fx = f[i*3+0], fy = f[i*3+1], fz = f[i*3+2];
        sfi[i] = make_float4(fx, fy, fz, 0.0f);
    } else if (q == 1) {
        float fx = f[i*3+0], fy = f[i*3+1], fz = f[i*3+2];
        const float* op = oprss + (size_t)(b * KOPS + k) * 9;
        // same source expression as R2 (bit-exact validated)
        float gx = wrap01(fx*op[0] + fy*op[1] + fz*op[2]);
        float gy = wrap01(fx*op[3] + fy*op[4] + fz*op[5]);
        float gz = wrap01(fx*op[6] + fy*op[7] + fz*op[8]);
        sfo[i] = make_float4(gx, gy, gz, 0.0f);
    }
    __syncthreads();

    const float4 fi4 = sfi[i];
    const float4 fo4 = sfo[i];

    // half-shell, weight 2: this thread covers t = q*32+1 .. q*32+32
    float a0 = 0.f, a1 = 0.f, a2 = 0.f;   // identity
    float c0 = 0.f, c1 = 0.f, c2 = 0.f;   // op-k
    const int tbase = q * 32 + 1;
    #pragma unroll 8
    for (int u = 0; u < 32; ++u) {
        const int j = (i + tbase + u) & (NATOMS - 1);
        {   // identity set
            const float4 fj = sfi[j];
            float dx = fj.x - fi4.x, dy = fj.y - fi4.y, dz = fj.z - fi4.z;
            float vx = (fj.x - rintf(dx)) - fi4.x;
            float vy = (fj.y - rintf(dy)) - fi4.y;
            float vz = (fj.z - rintf(dz)) - fi4.z;
            float px = vx*vx, py = vy*vy, pz = vz*vz;
            float d2 = px + py + pz;
            float m = (d2 <= 0.4f*0.4f) ? 1.0f : 0.0f;
            a0 = fmaf(px, m, a0);
            a1 = fmaf(py, m, a1);
            a2 = fmaf(pz, m, a2);
        }
        {   // op set
            const float4 fj = sfo[j];
            float dx = fj.x - fo4.x, dy = fj.y - fo4.y, dz = fj.z - fo4.z;
            float vx = (fj.x - rintf(dx)) - fo4.x;
            float vy = (fj.y - rintf(dy)) - fo4.y;
            float vz = (fj.z - rintf(dz)) - fo4.z;
            float px = vx*vx, py = vy*vy, pz = vz*vz;
            float d2 = px + py + pz;
            float m = (d2 <= 0.4f*0.4f) ? 1.0f : 0.0f;
            c0 = fmaf(px, m, c0);
            c1 = fmaf(py, m, c1);
            c2 = fmaf(pz, m, c2);
        }
    }
    a0 *= 2.0f; a1 *= 2.0f; a2 *= 2.0f;
    c0 *= 2.0f; c1 *= 2.0f; c2 *= 2.0f;

    // t=128 was counted at weight 2 by q==3; net weight must be 1.
    if (q == 3) {
        const int j = (i + 128) & (NATOMS - 1);
        {
            const float4 fj = sfi[j];
            float dx = fj.x - fi4.x, dy = fj.y - fi4.y, dz = fj.z - fi4.z;
            float vx = (fj.x - rintf(dx)) - fi4.x;
            float vy = (fj.y - rintf(dy)) - fi4.y;
            float vz = (fj.z - rintf(dz)) - fi4.z;
            float px = vx*vx, py = vy*vy, pz = vz*vz;
            float d2 = px + py + pz;
            float m = (d2 <= 0.4f*0.4f) ? 1.0f : 0.0f;
            a0 = fmaf(px, -m, a0);
            a1 = fmaf(py, -m, a1);
            a2 = fmaf(pz, -m, a2);
        }
        {
            const float4 fj = sfo[j];
            float dx = fj.x - fo4.x, dy = fj.y - fo4.y, dz = fj.z - fo4.z;
            float vx = (fj.x - rintf(dx)) - fo4.x;
            float vy = (fj.y - rintf(dy)) - fo4.y;
            float vz = (fj.z - rintf(dz)) - fo4.z;
            float px = vx*vx, py = vy*vy, pz = vz*vz;
            float d2 = px + py + pz;
            float m = (d2 <= 0.4f*0.4f) ? 1.0f : 0.0f;
            c0 = fmaf(px, -m, c0);
            c1 = fmaf(py, -m, c1);
            c2 = fmaf(pz, -m, c2);
        }
    }

    // reduce (s_k - s_0) = sum over threads of (c - a)   [linearity]
    float d0 = c0 - a0, d1 = c1 - a1, d2 = c2 - a2;
    for (int off = 32; off >= 1; off >>= 1) {
        d0 += __shfl_xor(d0, off);
        d1 += __shfl_xor(d1, off);
        d2 += __shfl_xor(d2, off);
    }
    __shared__ float part[16][3];
    const int wave = tid >> 6;
    if ((tid & 63) == 0) { part[wave][0] = d0; part[wave][1] = d1; part[wave][2] = d2; }
    __syncthreads();

    if (tid == 0) {
        float sx = 0.f, sy = 0.f, sz = 0.f;
        #pragma unroll
        for (int w = 0; w < 16; ++w) {
            sx += part[w][0]; sy += part[w][1]; sz += part[w][2];
        }
        float v = sqrtf(sx*sx + sy*sy + sz*sz);

        // ---- wait-free cross-block combine (no fences) ----
        // 1) accumulate into device-scope atomic float
        float old = atomicAdd(acc, v * (1.0f / 256.0f));
        // 2) launder `old`: forces completion of the add before the dec
        //    issues (compiler must materialize old -> s_waitcnt vmcnt), and
        //    "memory" pins ordering of the following atomic.
        asm volatile("" : : "v"(old) : "memory");
        // 3) arrival tick. atomicDec wrap: old==0 || old>255 -> 255 else -1.
        //    Self-heals from 0 (fresh/steady) and 0xAAAAAAAA (poison):
        //    in all cases exactly the 256th arrival sees old==1, leaving 0.
        unsigned int o2 = atomicDec(ctr, 255u);
        if (o2 == 1u) {
            // last arrival: all 256 adds are applied at the coherent point.
            float s = atomicExch(acc, 0.0f);   // read full sum + reset to 0
            out[0] = s;
        }
    }
}

extern "C" void kernel_launch(void* const* d_in, const int* in_sizes, int n_in,
                              void* d_out, int out_size, void* d_ws, size_t ws_size,
                              hipStream_t stream) {
    const float* fracs = (const float*)d_in[0];
    const float* oprss = (const float*)d_in[2];
    float* out = (float*)d_out;
    float* acc        = (float*)d_ws;                         // ws + 0
    unsigned int* ctr = (unsigned int*)((char*)d_ws + 128);   // ws + 128

    sgo_kernel<<<NB * KOPS, 1024, 0, stream>>>(fracs, oprss, acc, ctr, out);
}

// Round 6
// 14.820 us; speedup vs baseline: 1.9906x; 1.4275x over previous
//
#include <hip/hip_runtime.h>
#include <math.h>

// SGO_Loss_Prod: B=16, N=256 atoms, K=16 ops, r=0.4.
// Min-image collapse (r<0.5): at most one periodic shift passes the mask ->
// compute minimum image directly (validated R1/R2, absmax 0.0).
// R6: two-kernel structure (R2-proven; fused atomic tails cost ~10us, R3/R5).
//  - min-image via v = d - rint(d): 9 insts (was 12); d-s exact (Sterbenz),
//    mirror symmetry ev(u->v)==ev(v->u) now BIT-exact (negation exact).
//  - even/odd register blocking: thread owns atoms A=2i, B=2i+1; one LDS read
//    fj = coords[2i+t] serves both evals (offsets t, t-1) -> LDS reads halved.
//  - weight accounting: main t=2..129 uniform weight-2 (acc2); epilogue adds
//    t=1 (pair {2i,2i+1}) and subtracts one copy of t=128/129 (acc1) so
//    d=128-class pairs net weight 1. Wrap pairs covered by A-side t<=129
//    against doubled (halo) LDS arrays.
//  - sfE/sfO split arrays: t-parity compile-time (tbase even) -> stride-1
//    ds_read_b128, immediate offsets, no per-iter address math.

#define NATOMS 256
#define KOPS   16
#define NB     16
#define TPB    17              // tasks per structure: identity + 16 ops
#define NTASK  (NB * TPB)      // 272
#define NBLK   (NTASK * 2)     // 544 blocks (t-range split in 2)

// Replicates jnp.mod(x, 1.0) (validated bit-exact in R1).
__device__ __forceinline__ float wrap01(float x) {
    float m = fmodf(x, 1.0f);
    if (m < 0.0f) m += 1.0f;
    return m;
}

__global__ __launch_bounds__(256) void pair_kernel(
    const float* __restrict__ fracs,
    const float* __restrict__ oprss,
    float* __restrict__ sums)        // [NBLK][3]
{
    const int blk  = blockIdx.x;     // 0..543
    const int task = blk >> 1;       // 0..271
    const int q    = blk & 1;        // t-range half
    const int b    = task / TPB;
    const int tt   = task - b * TPB; // 0 = identity, 1..16 = op tt-1

    const int tid = threadIdx.x;     // 0..255
    const int h   = tid >> 7;        // sub-half of t-range
    const int i   = tid & 127;       // thread's atom pair index

    const float* f = fracs + (size_t)b * NATOMS * 3;

    __shared__ float4 sfE[256];      // atom 2x   at [x], halo [128+x]=[x], x<64
    __shared__ float4 sfO[256];      // atom 2x+1 at [x], halo likewise

    {   // stage atom `tid`
        float fx = f[tid*3+0], fy = f[tid*3+1], fz = f[tid*3+2];
        if (tt > 0) {
            const float* op = oprss + (size_t)(b * KOPS + tt - 1) * 9;
            float gx = wrap01(fx*op[0] + fy*op[1] + fz*op[2]);
            float gy = wrap01(fx*op[3] + fy*op[4] + fz*op[5]);
            float gz = wrap01(fx*op[6] + fy*op[7] + fz*op[8]);
            fx = gx; fy = gy; fz = gz;
        }
        float4 v4 = make_float4(fx, fy, fz, 0.0f);
        if (tid & 1) sfO[tid >> 1] = v4; else sfE[tid >> 1] = v4;
        if (tid < 128) {   // halo: atoms 0..127 duplicated at slots 128..191
            if (tid & 1) sfO[128 + (tid >> 1)] = v4; else sfE[128 + (tid >> 1)] = v4;
        }
    }
    __syncthreads();

    const float4 fa = sfE[i];        // atom A = 2i
    const float4 fb = sfO[i];        // atom B = 2i+1

    float a2x = 0.f, a2y = 0.f, a2z = 0.f;   // weight-2 bank
    float a1x = 0.f, a1y = 0.f, a1z = 0.f;   // weight-1 correction bank

#define EVAL_INTO(FJ, S, AX, AY, AZ, SGN) do {                                 \
        float dx = (FJ).x - (S).x, dy = (FJ).y - (S).y, dz = (FJ).z - (S).z;   \
        float vx = dx - rintf(dx), vy = dy - rintf(dy), vz = dz - rintf(dz);   \
        float px = vx*vx, py = vy*vy, pz = vz*vz;                              \
        float d2 = px + py + pz;                                               \
        float m  = (d2 <= 0.16f) ? (SGN) : 0.0f;                               \
        AX = fmaf(px, m, AX); AY = fmaf(py, m, AY); AZ = fmaf(pz, m, AZ);      \
    } while (0)

    // main loop: t = tbase..tbase+31 (tbase = 2 + (q*2+h)*32, always even).
    // even t -> sfE[i + t/2], odd t -> sfO[i + (t-1)/2]; both = ebase + u/2.
    // One read serves eval(A=2i -> j=2i+t) and eval(B=2i+1 -> j), weight 2.
    const int ebase = i + ((2 + (q*2 + h) * 32) >> 1);
    #pragma unroll
    for (int u = 0; u < 32; u += 2) {
        {   // even t
            const float4 fj = sfE[ebase + (u >> 1)];
            EVAL_INTO(fj, fa, a2x, a2y, a2z, 1.0f);
            EVAL_INTO(fj, fb, a2x, a2y, a2z, 1.0f);
        }
        {   // odd t
            const float4 fj = sfO[ebase + (u >> 1)];
            EVAL_INTO(fj, fa, a2x, a2y, a2z, 1.0f);
            EVAL_INTO(fj, fb, a2x, a2y, a2z, 1.0f);
        }
    }

    // epilogue (only the q==1,h==1 quadrant, whose main range hit t=128,129):
    //  t=1: pair {2i, 2i+1}, weight 2 (fj == fb, no read; B-side o=0 is self).
    //  t=128,129: main counted them at weight 2; subtract one copy -> net 1.
    if (q == 1 && h == 1) {
        EVAL_INTO(fb, fa, a2x, a2y, a2z, 1.0f);              // t = 1
        {   const float4 fj = sfE[i + 64];                   // t = 128
            EVAL_INTO(fj, fa, a1x, a1y, a1z, -1.0f);
            EVAL_INTO(fj, fb, a1x, a1y, a1z, -1.0f);
        }
        {   const float4 fj = sfO[i + 64];                   // t = 129
            EVAL_INTO(fj, fa, a1x, a1y, a1z, -1.0f);
            EVAL_INTO(fj, fb, a1x, a1y, a1z, -1.0f);
        }
    }
#undef EVAL_INTO

    float cx = fmaf(2.0f, a2x, a1x);
    float cy = fmaf(2.0f, a2y, a1y);
    float cz = fmaf(2.0f, a2z, a1z);

    // wave64 butterfly reduce
    for (int off = 32; off >= 1; off >>= 1) {
        cx += __shfl_xor(cx, off);
        cy += __shfl_xor(cy, off);
        cz += __shfl_xor(cz, off);
    }
    __shared__ float part[4][3];
    const int wave = tid >> 6;
    if ((tid & 63) == 0) { part[wave][0] = cx; part[wave][1] = cy; part[wave][2] = cz; }
    __syncthreads();
    if (tid == 0) {
        float* dst = sums + (size_t)blk * 3;
        dst[0] = part[0][0] + part[1][0] + part[2][0] + part[3][0];
        dst[1] = part[0][1] + part[1][1] + part[2][1] + part[3][1];
        dst[2] = part[0][2] + part[1][2] + part[2][2] + part[3][2];
    }
}

__global__ __launch_bounds__(256) void finish_kernel(
    const float* __restrict__ sums, float* __restrict__ out)
{
    const int t = threadIdx.x;        // 0..255 -> (b,k)
    const int b = t >> 4, k = t & 15;
    const float* s0p = sums + (size_t)((b * TPB + 0)     * 2) * 3;
    const float* skp = sums + (size_t)((b * TPB + 1 + k) * 2) * 3;
    float s0x = 0.f, s0y = 0.f, s0z = 0.f;
    float skx = 0.f, sky = 0.f, skz = 0.f;
    #pragma unroll
    for (int qq = 0; qq < 2; ++qq) {
        s0x += s0p[qq*3+0]; s0y += s0p[qq*3+1]; s0z += s0p[qq*3+2];
        skx += skp[qq*3+0]; sky += skp[qq*3+1]; skz += skp[qq*3+2];
    }
    float d0 = skx - s0x, d1 = sky - s0y, d2 = skz - s0z;
    float v = sqrtf(d0*d0 + d1*d1 + d2*d2);

    for (int off = 32; off >= 1; off >>= 1) v += __shfl_xor(v, off);
    __shared__ float part[4];
    if ((t & 63) == 0) part[t >> 6] = v;
    __syncthreads();
    if (t == 0) out[0] = (part[0] + part[1] + part[2] + part[3]) * (1.0f / 256.0f);
}

extern "C" void kernel_launch(void* const* d_in, const int* in_sizes, int n_in,
                              void* d_out, int out_size, void* d_ws, size_t ws_size,
                              hipStream_t stream) {
    const float* fracs = (const float*)d_in[0];
    const float* oprss = (const float*)d_in[2];
    float* out  = (float*)d_out;
    float* sums = (float*)d_ws;      // NBLK*3 floats = 6528 B

    pair_kernel<<<NBLK, 256, 0, stream>>>(fracs, oprss, sums);
    finish_kernel<<<1, 256, 0, stream>>>(sums, out);
}